// Round 9
// baseline (188.421 us; speedup 1.0000x reference)
//
#include <hip/hip_runtime.h>
#include <math.h>

typedef __attribute__((ext_vector_type(8))) short short8;
typedef __attribute__((ext_vector_type(4))) float f32x4;
typedef __attribute__((ext_vector_type(2))) unsigned int u32x2;

#define AS1 __attribute__((address_space(1)))
#define AS3 __attribute__((address_space(3)))

__device__ __forceinline__ float b2f(short s){
  return __uint_as_float(((unsigned int)(unsigned short)s) << 16);
}
__device__ __forceinline__ short f2b(float f){
  unsigned int u = __float_as_uint(f);
  u = (u + 0x7fffu + ((u >> 16) & 1u)) >> 16;
  return (short)u;
}
__device__ __forceinline__ unsigned pk2(float lo, float hi){
  return ((unsigned)(unsigned short)f2b(hi) << 16) | (unsigned)(unsigned short)f2b(lo);
}

// ---------------- weight f32 -> bf16 conversion ----------------
__global__ __launch_bounds__(256) void cvt_w(
    const float* __restrict__ s0, const float* __restrict__ s1,
    const float* __restrict__ s2, const float* __restrict__ s3,
    const float* __restrict__ s4, const float* __restrict__ s5,
    short* __restrict__ dst)
{
  const float* srcs[6] = {s0, s1, s2, s3, s4, s5};
  int i = blockIdx.x * 256 + threadIdx.x;       // 6*65536 total
  dst[i] = f2b(srcs[i >> 16][i & 65535]);
}

// ---------------- GEMM, A-in-registers: C[M,256] = A[M,256] @ W^T + b --------
// Block = 64 rows x 256 cols, 4 waves (wave: 16 rows, acc[16] f32x4).
// Lane owns its A row fragments directly (no A LDS, no A barrier);
// LN fused in-register (LNA=1: f32 src, LNA=2: bf16 src) via 4-lane shfl.
// LDS = W k-slice double buffer only (40KB) -> 3 blocks/CU.
// Epilogue: GELU / residual (RES=1 f32, RES=2 bf16) / f32 out / bf16 out /
//           kfrag (OT=1) / vfrag (OT=2) / qfrag (OT=3).
template<int RES, int GELU, int OF, int OB, int OT, int LNA>
__global__ __launch_bounds__(256, 3) void gemmR(
    const short* __restrict__ A, const float* __restrict__ Af,
    const short* __restrict__ W,
    const float* __restrict__ bias,
    const float* __restrict__ resF, const short* __restrict__ resB,
    float* __restrict__ outF, short* __restrict__ outB,
    const float* __restrict__ lnag, const float* __restrict__ lnab)
{
  __shared__ short Ws[2][256][40];     // k-slice double buffer
  const int tid = threadIdx.x;
  const int m0 = blockIdx.x << 6;
  const int w = tid >> 6, lane = tid & 63;
  const int l15 = lane & 15, g = lane >> 4;
  const size_t myrow = (size_t)m0 + (w << 4) + l15;

  // ---- A fragments into registers (lane: row myrow, cols s*32+g*8..+8) ----
  short8 afr[8];
  if (LNA == 0){
    #pragma unroll
    for (int s = 0; s < 8; ++s)
      afr[s] = *(const short8*)&A[myrow * 256 + (s << 5) + (g << 3)];
  } else {
    float vv[64];
    if (LNA == 1){
      #pragma unroll
      for (int s = 0; s < 8; ++s){
        *(f32x4*)&vv[8 * s]     = *(const f32x4*)&Af[myrow * 256 + (s << 5) + (g << 3)];
        *(f32x4*)&vv[8 * s + 4] = *(const f32x4*)&Af[myrow * 256 + (s << 5) + (g << 3) + 4];
      }
    } else {
      #pragma unroll
      for (int s = 0; s < 8; ++s){
        short8 t = *(const short8*)&A[myrow * 256 + (s << 5) + (g << 3)];
        #pragma unroll
        for (int j = 0; j < 8; ++j) vv[8 * s + j] = b2f(t[j]);
      }
    }
    float s1 = 0.f, s2 = 0.f;
    #pragma unroll
    for (int i = 0; i < 64; ++i){ s1 += vv[i]; s2 += vv[i] * vv[i]; }
    s1 += __shfl_xor(s1, 16); s2 += __shfl_xor(s2, 16);   // partners share l15
    s1 += __shfl_xor(s1, 32); s2 += __shfl_xor(s2, 32);
    const float mu = s1 * 0.00390625f;
    const float rs = rsqrtf(s2 * 0.00390625f - mu * mu + 1e-5f);
    #pragma unroll
    for (int s = 0; s < 8; ++s){
      const int c0 = (s << 5) + (g << 3);
      f32x4 g0 = *(const f32x4*)&lnag[c0], g1 = *(const f32x4*)&lnag[c0 + 4];
      f32x4 b0 = *(const f32x4*)&lnab[c0], b1 = *(const f32x4*)&lnab[c0 + 4];
      short8 o;
      #pragma unroll
      for (int j = 0; j < 4; ++j) o[j] = f2b((vv[8 * s + j] - mu) * rs * g0[j] + b0[j]);
      #pragma unroll
      for (int j = 0; j < 4; ++j) o[4 + j] = f2b((vv[8 * s + 4 + j] - mu) * rs * g1[j] + b1[j]);
      afr[s] = o;
    }
  }

  // ---- stage W k0=0 ----
  #pragma unroll
  for (int it = 0; it < 4; ++it){
    int row = (it << 6) + (tid >> 2), c = (tid & 3) << 3;
    *(short8*)&Ws[0][row][c] = *(const short8*)&W[(size_t)row * 256 + c];
  }
  __syncthreads();

  f32x4 acc[16];
  #pragma unroll
  for (int nt = 0; nt < 16; ++nt) acc[nt] = {0.f, 0.f, 0.f, 0.f};

  int cur = 0;
  for (int s = 0; s < 8; ++s){
    const int k0 = s << 5;
    short8 wreg[4];
    if (s < 7){
      #pragma unroll
      for (int it = 0; it < 4; ++it)
        wreg[it] = *(const short8*)&W[(size_t)((it << 6) + (tid >> 2)) * 256 + k0 + 32 + ((tid & 3) << 3)];
    }
    const short8 af = afr[s];
    #pragma unroll
    for (int nt = 0; nt < 16; ++nt){
      short8 bf = *(const short8*)&Ws[cur][(nt << 4) + l15][g << 3];
      acc[nt] = __builtin_amdgcn_mfma_f32_16x16x32_bf16(af, bf, acc[nt], 0, 0, 0);
    }
    if (s < 7){
      #pragma unroll
      for (int it = 0; it < 4; ++it)
        *(short8*)&Ws[cur ^ 1][(it << 6) + (tid >> 2)][(tid & 3) << 3] = wreg[it];
    }
    __syncthreads();
    cur ^= 1;
  }

  const int row_l = (w << 4) + (g << 2);     // + r = wave's row within block
  #pragma unroll
  for (int nt = 0; nt < 16; ++nt){
    const int col = (nt << 4) + l15;
    const float bv = bias[col];
    #pragma unroll
    for (int r = 0; r < 4; ++r){
      const int m = m0 + row_l + r;
      const size_t idx = (size_t)m * 256 + col;
      float v = acc[nt][r] + bv;
      if (GELU) v = 0.5f * v * (1.0f + erff(v * 0.70710678118f));
      if (RES == 1) v += resF[idx];
      if (RES == 2) v += b2f(resB[idx]);
      if (OF) outF[idx] = v;
      if (OB) outB[idx] = f2b(v);
      if (OT == 1){   // kfrag: [b][h][nt][half][g][l15][8]
        const int b_ = m >> 8, kvr = m & 255;
        const int knt = kvr >> 4, kl = kvr & 15;
        const int h = col >> 6, half = (col >> 5) & 1, kg = (col >> 3) & 3, kj = col & 7;
        outB[(((((size_t)(b_ * 4 + h) * 16 + knt) * 2 + half) * 4 + kg) * 16 + kl) * 8 + kj] = f2b(v);
      }
      if (OT == 2){   // vfrag: [b][h][kk][n2][g][l15][8]
        const int b_ = m >> 8, kvj = m & 255;
        const int jp = (kvj & ~31) | (((kvj >> 2) & 3) << 3) | (((kvj >> 4) & 1) << 2) | (kvj & 3);
        const int h = col >> 6, dp = col & 63;
        const int kk = jp >> 5, vg = (jp >> 3) & 3, vj = jp & 7;
        const int vn2 = dp >> 4, vl = dp & 15;
        outB[(((((size_t)(b_ * 4 + h) * 8 + kk) * 4 + vn2) * 4 + vg) * 16 + vl) * 8 + vj] = f2b(v);
      }
      if (OT == 3){   // qfrag: [m>>4][h][half][gq*16+l15q][8]
        const int l15q = m & 15;
        const int h = col >> 6, half = (col >> 5) & 1, gq = (col >> 3) & 3, j = col & 7;
        outB[((((size_t)(m >> 4) * 4 + h) * 2 + half) * 64 + gq * 16 + l15q) * 8 + j] = f2b(v);
      }
    }
  }
}

// ---------------- fused MFMA attention ----------------
// Block: 256 thr = 4 waves x 16 q-rows; grid 64x8 = 512 blocks (2/CU).
// LDS 64KB: K buf 32KB | V buf 32KB, split-phase staging (V stages under QK,
// next-K under softmax+PV). cw loaded with full-row 1KB bursts -> LDS bounce
// (XOR swizzle) -> packed regs. Q read from frag-order buffer (coalesced).
// am written via LDS bounce -> 1KB-burst stores.
__global__ __launch_bounds__(256, 2) void attn_k(
    const short* __restrict__ Qf, const short* __restrict__ Kf,
    const short* __restrict__ Vf, const float* __restrict__ cw,
    short* __restrict__ ctx, float* __restrict__ am_out)
{
  extern __shared__ __align__(16) short smem[];   // 32768 shorts = 64KB
  short* Kl = smem;
  short* Vl = smem + 16384;
  const int b = blockIdx.y;
  const int q0 = blockIdx.x << 6;
  const int tid = threadIdx.x;
  const int w = tid >> 6, lane = tid & 63;
  const int l15 = lane & 15, g = lane >> 4;
  const size_t qw = (size_t)b * 4096 + q0 + (w << 4);   // wave's first q row
  const size_t qblk = qw >> 4;

#define STG(dst_, src_) do{ _Pragma("unroll")                                        \
  for (int it_ = 0; it_ < 8; ++it_){ int c_ = (it_ << 8) + tid;                      \
    __builtin_amdgcn_global_load_lds((const AS1 void*)((src_) + (c_ << 3)),          \
                                     (AS3 void*)((dst_) + (c_ << 3)), 16, 0, 0); } }while(0)

  // ---- cw: full-row coalesced load -> swizzled LDS -> scattered reg read ----
  unsigned cwp[16][2];
  f32x4 am[16];
  {
    char* reg = (char*)smem + (w << 13);       // 8KB per wave
    #pragma unroll
    for (int j = 0; j < 16; ++j){
      f32x4 v = *(const f32x4*)&cw[(qw + j) * 256 + (lane << 2)];  // 1KB burst/instr
      u32x2 d = { pk2(v[0], v[1]), pk2(v[2], v[3]) };
      unsigned off = ((j << 9) + (lane << 3)) ^ ((j & 7) << 4);
      *(u32x2*)(reg + off) = d;
    }
    __syncthreads();
    #pragma unroll
    for (int nt = 0; nt < 16; ++nt){
      unsigned base = ((l15 << 9) + (nt << 5) + (g << 3)) ^ ((l15 & 7) << 4);
      cwp[nt][0] = *(const unsigned*)(reg + base);
      cwp[nt][1] = *(const unsigned*)(reg + base + 4);
      am[nt] = {0.f, 0.f, 0.f, 0.f};
    }
    __syncthreads();
  }

  STG(Kl, Kf + ((size_t)(b * 4) << 14));
  __syncthreads();                       // K(0) staged

  for (int h = 0; h < 4; ++h){
    STG(Vl, Vf + ((size_t)(b * 4 + h) << 14));          // V(h) under QK
    short8 qf0 = *(const short8*)&Qf[(((qblk * 4 + h) * 2 + 0) * 64 + lane) * 8];
    short8 qf1 = *(const short8*)&Qf[(((qblk * 4 + h) * 2 + 1) * 64 + lane) * 8];

    // ---- scores: swapped operands, lane-contiguous ds_read_b128 ----
    f32x4 acc[16];
    #pragma unroll
    for (int nt = 0; nt < 16; ++nt) acc[nt] = {0.f, 0.f, 0.f, 0.f};
    #pragma unroll
    for (int nt = 0; nt < 16; ++nt){
      short8 kf0 = *(const short8*)&Kl[(nt << 10) + (lane << 3)];
      acc[nt] = __builtin_amdgcn_mfma_f32_16x16x32_bf16(kf0, qf0, acc[nt], 0, 0, 0);
      short8 kf1 = *(const short8*)&Kl[(nt << 10) + 512 + (lane << 3)];
      acc[nt] = __builtin_amdgcn_mfma_f32_16x16x32_bf16(kf1, qf1, acc[nt], 0, 0, 0);
    }
    __syncthreads();                     // V(h) ready; all waves done with Kl
    if (h < 3) STG(Kl, Kf + ((size_t)(b * 4 + h + 1) << 14));   // K(h+1) under softmax+PV

    // ---- softmax, fully in-lane (row q = l15; partners at lane^16, lane^32) ----
    float mx = -3.4e38f;
    #pragma unroll
    for (int nt = 0; nt < 16; ++nt){
      float c0 = __uint_as_float(cwp[nt][0] << 16);
      float c1 = __uint_as_float(cwp[nt][0] & 0xffff0000u);
      float c2 = __uint_as_float(cwp[nt][1] << 16);
      float c3 = __uint_as_float(cwp[nt][1] & 0xffff0000u);
      acc[nt][0] = acc[nt][0] * 0.125f + c0;
      acc[nt][1] = acc[nt][1] * 0.125f + c1;
      acc[nt][2] = acc[nt][2] * 0.125f + c2;
      acc[nt][3] = acc[nt][3] * 0.125f + c3;
      mx = fmaxf(mx, fmaxf(fmaxf(acc[nt][0], acc[nt][1]), fmaxf(acc[nt][2], acc[nt][3])));
    }
    mx = fmaxf(mx, __shfl_xor(mx, 16));
    mx = fmaxf(mx, __shfl_xor(mx, 32));
    float sm = 0.f;
    #pragma unroll
    for (int nt = 0; nt < 16; ++nt){
      #pragma unroll
      for (int r = 0; r < 4; ++r){
        float e = __expf(acc[nt][r] - mx);
        acc[nt][r] = e; sm += e;
      }
    }
    sm += __shfl_xor(sm, 16);
    sm += __shfl_xor(sm, 32);
    float inv = 1.f / sm;
    #pragma unroll
    for (int nt = 0; nt < 16; ++nt){
      #pragma unroll
      for (int r = 0; r < 4; ++r){
        float p = acc[nt][r] * inv;
        acc[nt][r] = p;
        am[nt][r] += 0.25f * p;
      }
    }
    // ---- ctx = P @ V : in-lane A packs; lane-contiguous V ds_reads ----
    f32x4 oc[4] = {{0,0,0,0},{0,0,0,0},{0,0,0,0},{0,0,0,0}};
    #pragma unroll
    for (int kk = 0; kk < 8; ++kk){
      union { short8 s; unsigned u[4]; } pa;
      pa.u[0] = pk2(acc[2 * kk][0],     acc[2 * kk][1]);
      pa.u[1] = pk2(acc[2 * kk][2],     acc[2 * kk][3]);
      pa.u[2] = pk2(acc[2 * kk + 1][0], acc[2 * kk + 1][1]);
      pa.u[3] = pk2(acc[2 * kk + 1][2], acc[2 * kk + 1][3]);
      #pragma unroll
      for (int n2 = 0; n2 < 4; ++n2){
        short8 vb = *(const short8*)&Vl[(((kk << 2) + n2) << 9) + (lane << 3)];
        oc[n2] = __builtin_amdgcn_mfma_f32_16x16x32_bf16(pa.s, vb, oc[n2], 0, 0, 0);
      }
    }
    #pragma unroll
    for (int n2 = 0; n2 < 4; ++n2)
      #pragma unroll
      for (int r = 0; r < 4; ++r)
        ctx[(qw + (g << 2) + r) * 256 + (h << 6) + (n2 << 4) + l15] = f2b(oc[n2][r]);

    __syncthreads();                     // K(h+1) ready; all waves done with Vl
  }

  // ---- am: scatter into swizzled LDS, then 1KB-burst coalesced stores ----
  {
    char* reg = (char*)smem + (w << 14);       // 16KB per wave (f32)
    #pragma unroll
    for (int nt = 0; nt < 16; ++nt){
      unsigned off = ((l15 << 10) + (nt << 6) + (g << 4)) ^ ((l15 & 7) << 4);
      *(f32x4*)(reg + off) = am[nt];
    }
    __syncthreads();
    #pragma unroll
    for (int i2 = 0; i2 < 16; ++i2){
      unsigned fb = (tid << 4) + (i2 << 12);   // flat byte 0..65535
      unsigned rowin = (fb >> 10) & 15;
      f32x4 v = *(const f32x4*)((char*)smem + (fb ^ ((rowin & 7) << 4)));
      unsigned row = fb >> 10;                  // 0..63 within block
      *(f32x4*)&am_out[((size_t)b * 4096 + q0 + row) * 256 + ((fb & 1023) >> 2)] = v;
    }
  }
#undef STG
}

extern "C" void kernel_launch(void* const* d_in, const int* in_sizes, int n_in,
                              void* d_out, int out_size, void* d_ws, size_t ws_size,
                              hipStream_t stream)
{
  const float* node_emb = (const float*)d_in[0];
  const float* cluster  = (const float*)d_in[1];
  const float* cw       = (const float*)d_in[2];
  const float* ln_q_g   = (const float*)d_in[3];
  const float* ln_q_b   = (const float*)d_in[4];
  const float* ln_kv_g  = (const float*)d_in[5];
  const float* ln_kv_b  = (const float*)d_in[6];
  const float* ln_o_g   = (const float*)d_in[7];
  const float* ln_o_b   = (const float*)d_in[8];
  const float* W_q  = (const float*)d_in[9];  const float* b_q  = (const float*)d_in[10];
  const float* W_k  = (const float*)d_in[11]; const float* b_k  = (const float*)d_in[12];
  const float* W_v  = (const float*)d_in[13]; const float* b_v  = (const float*)d_in[14];
  const float* W_o  = (const float*)d_in[15]; const float* b_o  = (const float*)d_in[16];
  const float* W_m1 = (const float*)d_in[17]; const float* b_m1 = (const float*)d_in[18];
  const float* W_m2 = (const float*)d_in[19]; const float* b_m2 = (const float*)d_in[20];

  char* ws = (char*)d_ws;
  short* Wbf   = (short*)ws;                                   // 786,432 B (6 x 64K bf16)
  short* n1    = (short*)(ws + 786432);                        // 16.78 MB: ctx -> h1
  short* n2    = (short*)(ws + 786432 + 16777216);             // 16.78 MB: Qfrag -> x (bf16)
  short* kfrag = (short*)(ws + 786432 + 2 * 16777216 + 1048576);
  short* vfrag = (short*)(ws + 786432 + 2 * 16777216 + 2 * 1048576);

  float* outF = (float*)d_out;            // first half: final out (written only by M2)
  float* amof = (float*)d_out + 8388608;  // second half: attn_matrix

  hipFuncSetAttribute((const void*)attn_k, hipFuncAttributeMaxDynamicSharedMemorySize, 65536);

  cvt_w<<<1536, 256, 0, stream>>>(W_q, W_k, W_v, W_o, W_m1, W_m2, Wbf);
  // Q projection: fused input-LN, frag-order output -> n2
  gemmR<0,0,0,0,3,1><<<512, 256, 0, stream>>>(nullptr, node_emb, Wbf, b_q,
      nullptr, nullptr, nullptr, n2, ln_q_g, ln_q_b);
  // K / V projections: fused kv-LN from cluster, frag-order outputs
  gemmR<0,0,0,0,1,1><<<32, 256, 0, stream>>>(nullptr, cluster, Wbf + 65536, b_k,
      nullptr, nullptr, nullptr, kfrag, ln_kv_g, ln_kv_b);
  gemmR<0,0,0,0,2,1><<<32, 256, 0, stream>>>(nullptr, cluster, Wbf + 131072, b_v,
      nullptr, nullptr, nullptr, vfrag, ln_kv_g, ln_kv_b);
  // attention (ctx -> n1, attn_matrix -> d_out 2nd half)
  attn_k<<<dim3(64, 8), 256, 65536, stream>>>(n2, kfrag, vfrag, cw, n1, amof);
  // O proj + residual(node_emb f32) -> x as bf16 into n2 (Q dead)
  gemmR<1,0,0,1,0,0><<<512, 256, 0, stream>>>(n1, nullptr, Wbf + 196608, b_o,
      node_emb, nullptr, nullptr, n2, nullptr, nullptr);
  // MLP1 with fused LN(x) prologue + GELU -> n1
  gemmR<0,1,0,1,0,2><<<512, 256, 0, stream>>>(n2, nullptr, Wbf + 262144, b_m1,
      nullptr, nullptr, nullptr, n1, ln_o_g, ln_o_b);
  // MLP2 + residual(x bf16) -> final out f32
  gemmR<2,0,1,0,0,0><<<512, 256, 0, stream>>>(n1, nullptr, Wbf + 327680, b_m2,
      nullptr, n2, outF, nullptr, nullptr, nullptr);
}

// Round 10
// 161.116 us; speedup vs baseline: 1.1695x; 1.1695x over previous
//
#include <hip/hip_runtime.h>
#include <math.h>

typedef __attribute__((ext_vector_type(8))) short short8;
typedef __attribute__((ext_vector_type(4))) float f32x4;
typedef __attribute__((ext_vector_type(2))) unsigned int u32x2;

#define AS1 __attribute__((address_space(1)))
#define AS3 __attribute__((address_space(3)))

__device__ __forceinline__ float b2f(short s){
  return __uint_as_float(((unsigned int)(unsigned short)s) << 16);
}
__device__ __forceinline__ short f2b(float f){
  unsigned int u = __float_as_uint(f);
  u = (u + 0x7fffu + ((u >> 16) & 1u)) >> 16;
  return (short)u;
}
__device__ __forceinline__ unsigned pk2(float lo, float hi){
  return ((unsigned)(unsigned short)f2b(hi) << 16) | (unsigned)(unsigned short)f2b(lo);
}

// ---------------- weight f32 -> bf16, permuted to STAGE ORDER ----------------
// Wst[mat][s][c][j] (c = it*256+tid, j=0..7) = W[mat][(it<<6)+(tid>>2)][s*32+(tid&3)*8+j]
// so gemmW's k-slice staging load for (it,tid) is the contiguous 16B at (s*8192+c*8).
__global__ __launch_bounds__(256) void cvt_w(
    const float* __restrict__ s0, const float* __restrict__ s1,
    const float* __restrict__ s2, const float* __restrict__ s3,
    const float* __restrict__ s4, const float* __restrict__ s5,
    short* __restrict__ dst)
{
  const float* srcs[6] = {s0, s1, s2, s3, s4, s5};
  int i = blockIdx.x * 256 + threadIdx.x;       // 6*65536 total
  int mat = i >> 16, rc = i & 65535;
  int row = rc >> 8, col = rc & 255;
  int d = mat * 65536 + ((col >> 5) << 13) + ((row >> 6) << 11)
        + ((row & 63) << 5) + (((col >> 3) & 3) << 3) + (col & 7);
  dst[d] = f2b(srcs[mat][rc]);
}

// ---------------- wide GEMM: C[M,256] = A[M,256] @ W[256,256]^T + b ----------------
// Block = 64 rows x 256 cols, 4 waves (wave: 16 rows, acc[16] f32x4).
// A staged once to padded LDS (LN fused: LNA=1 f32 src, LNA=2 bf16 src), then
// hoisted to afr[8] registers. W (stage-order Wst) double-buffered via
// global_load_lds (coalesced, zero staging regs); bf reads are 1KB-contiguous
// per instr (conflict-free, unpadded). 1 barrier per k-step.
// Epilogue: GELU / residual (RES=1 f32, RES=2 bf16) / f32 out / bf16 out /
//           kfrag (OT=1) / vfrag (OT=2) / qfrag (OT=3).
template<int RES, int GELU, int OF, int OB, int OT, int LNA>
__global__ __launch_bounds__(256, 2) void gemmW(
    const short* __restrict__ A, const float* __restrict__ Af,
    const short* __restrict__ Wst,
    const float* __restrict__ bias,
    const float* __restrict__ resF, const short* __restrict__ resB,
    float* __restrict__ outF, short* __restrict__ outB,
    const float* __restrict__ lnag, const float* __restrict__ lnab)
{
  __shared__ short As[64][264];        // padded (row stride 132 dwords = 4 mod 32)
  __shared__ short Ws[2][8192];        // unpadded k-slice dbuf: [row*32 + c]
  const int tid = threadIdx.x;
  const int m0 = blockIdx.x << 6;
  const int w = tid >> 6, lane = tid & 63;
  const int l15 = lane & 15, g = lane >> 4;

  // ---- stage A (once), optionally LayerNorm'd ----
  if (LNA){
    const int row = tid >> 2, c0 = (tid & 3) << 6;   // 4 threads/row, 64 cols each
    float vv[64];
    if (LNA == 1){
      const float* src = &Af[(size_t)(m0 + row) * 256 + c0];
      #pragma unroll
      for (int i = 0; i < 16; ++i) *(f32x4*)&vv[4 * i] = *(const f32x4*)&src[4 * i];
    } else {
      const short* src = &A[(size_t)(m0 + row) * 256 + c0];
      #pragma unroll
      for (int i = 0; i < 8; ++i){
        short8 s = *(const short8*)&src[8 * i];
        #pragma unroll
        for (int j = 0; j < 8; ++j) vv[8 * i + j] = b2f(s[j]);
      }
    }
    float s1 = 0.f, s2 = 0.f;
    #pragma unroll
    for (int i = 0; i < 64; ++i){ s1 += vv[i]; s2 += vv[i] * vv[i]; }
    s1 += __shfl_xor(s1, 1); s2 += __shfl_xor(s2, 1);
    s1 += __shfl_xor(s1, 2); s2 += __shfl_xor(s2, 2);
    const float mu = s1 * 0.00390625f;
    const float rs = rsqrtf(s2 * 0.00390625f - mu * mu + 1e-5f);
    #pragma unroll
    for (int i = 0; i < 8; ++i){
      f32x4 gv0 = *(const f32x4*)&lnag[c0 + 8 * i];
      f32x4 gv1 = *(const f32x4*)&lnag[c0 + 8 * i + 4];
      f32x4 bv0 = *(const f32x4*)&lnab[c0 + 8 * i];
      f32x4 bv1 = *(const f32x4*)&lnab[c0 + 8 * i + 4];
      short8 o;
      #pragma unroll
      for (int j = 0; j < 4; ++j) o[j] = f2b((vv[8 * i + j] - mu) * rs * gv0[j] + bv0[j]);
      #pragma unroll
      for (int j = 0; j < 4; ++j) o[4 + j] = f2b((vv[8 * i + 4 + j] - mu) * rs * gv1[j] + bv1[j]);
      *(short8*)&As[row][c0 + 8 * i] = o;
    }
  } else {
    #pragma unroll
    for (int it = 0; it < 8; ++it){
      int idx = tid + (it << 8);
      int row = idx >> 5, c = (idx & 31) << 3;
      *(short8*)&As[row][c] = *(const short8*)&A[(size_t)(m0 + row) * 256 + c];
    }
  }
  // ---- stage W slice 0 (async, coalesced) ----
  #pragma unroll
  for (int it = 0; it < 4; ++it){
    int c = (it << 8) + tid;
    __builtin_amdgcn_global_load_lds((const AS1 void*)(Wst + ((size_t)c << 3)),
                                     (AS3 void*)(&Ws[0][0] + (c << 3)), 16, 0, 0);
  }
  __syncthreads();

  // ---- hoist A fragments to registers ----
  short8 afr[8];
  #pragma unroll
  for (int s = 0; s < 8; ++s)
    afr[s] = *(const short8*)&As[(w << 4) + l15][(s << 5) + (g << 3)];

  f32x4 acc[16];
  #pragma unroll
  for (int nt = 0; nt < 16; ++nt) acc[nt] = {0.f, 0.f, 0.f, 0.f};

  int cur = 0;
  for (int s = 0; s < 8; ++s){
    if (s < 7){
      #pragma unroll
      for (int it = 0; it < 4; ++it){
        int c = (it << 8) + tid;
        __builtin_amdgcn_global_load_lds(
            (const AS1 void*)(Wst + (((size_t)(s + 1)) << 13) + ((size_t)c << 3)),
            (AS3 void*)(&Ws[cur ^ 1][0] + (c << 3)), 16, 0, 0);
      }
    }
    const short8 af = afr[s];
    #pragma unroll
    for (int nt = 0; nt < 16; ++nt){
      short8 bf = *(const short8*)&Ws[cur][((nt << 4) + l15) * 32 + (g << 3)];
      acc[nt] = __builtin_amdgcn_mfma_f32_16x16x32_bf16(af, bf, acc[nt], 0, 0, 0);
    }
    __syncthreads();
    cur ^= 1;
  }

  const int row_l = (w << 4) + (g << 2);     // + r = wave's row within block
  #pragma unroll
  for (int nt = 0; nt < 16; ++nt){
    const int col = (nt << 4) + l15;
    const float bv = bias[col];
    #pragma unroll
    for (int r = 0; r < 4; ++r){
      const int m = m0 + row_l + r;
      const size_t idx = (size_t)m * 256 + col;
      float v = acc[nt][r] + bv;
      if (GELU) v = 0.5f * v * (1.0f + erff(v * 0.70710678118f));
      if (RES == 1) v += resF[idx];
      if (RES == 2) v += b2f(resB[idx]);
      if (OF) outF[idx] = v;
      if (OB) outB[idx] = f2b(v);
      if (OT == 1){   // kfrag: [b][h][nt][half][g][l15][8]
        const int b_ = m >> 8, kvr = m & 255;
        const int knt = kvr >> 4, kl = kvr & 15;
        const int h = col >> 6, half = (col >> 5) & 1, kg = (col >> 3) & 3, kj = col & 7;
        outB[(((((size_t)(b_ * 4 + h) * 16 + knt) * 2 + half) * 4 + kg) * 16 + kl) * 8 + kj] = f2b(v);
      }
      if (OT == 2){   // vfrag: [b][h][kk][n2][g][l15][8]
        const int b_ = m >> 8, kvj = m & 255;
        const int jp = (kvj & ~31) | (((kvj >> 2) & 3) << 3) | (((kvj >> 4) & 1) << 2) | (kvj & 3);
        const int h = col >> 6, dp = col & 63;
        const int kk = jp >> 5, vg = (jp >> 3) & 3, vj = jp & 7;
        const int vn2 = dp >> 4, vl = dp & 15;
        outB[(((((size_t)(b_ * 4 + h) * 8 + kk) * 4 + vn2) * 4 + vg) * 16 + vl) * 8 + vj] = f2b(v);
      }
      if (OT == 3){   // qfrag: [m>>4][h][half][gq*16+l15q][8]
        const int l15q = m & 15;
        const int h = col >> 6, half = (col >> 5) & 1, gq = (col >> 3) & 3, j = col & 7;
        outB[((((size_t)(m >> 4) * 4 + h) * 2 + half) * 64 + gq * 16 + l15q) * 8 + j] = f2b(v);
      }
    }
  }
}

// ---------------- fused MFMA attention (r9 structure, kept) ----------------
// Block: 256 thr = 4 waves x 16 q-rows; grid 64x8 = 512 blocks (2/CU).
// LDS 64KB: K buf | V buf, split-phase staging (V stages under QK, next-K under
// softmax+PV). cw: 1KB-burst loads -> swizzled LDS bounce -> packed regs.
// Q from frag-order buffer. am via LDS bounce -> 1KB-burst stores.
__global__ __launch_bounds__(256, 2) void attn_k(
    const short* __restrict__ Qf, const short* __restrict__ Kf,
    const short* __restrict__ Vf, const float* __restrict__ cw,
    short* __restrict__ ctx, float* __restrict__ am_out)
{
  extern __shared__ __align__(16) short smem[];   // 32768 shorts = 64KB
  short* Kl = smem;
  short* Vl = smem + 16384;
  const int b = blockIdx.y;
  const int q0 = blockIdx.x << 6;
  const int tid = threadIdx.x;
  const int w = tid >> 6, lane = tid & 63;
  const int l15 = lane & 15, g = lane >> 4;
  const size_t qw = (size_t)b * 4096 + q0 + (w << 4);   // wave's first q row
  const size_t qblk = qw >> 4;

#define STG(dst_, src_) do{ _Pragma("unroll")                                        \
  for (int it_ = 0; it_ < 8; ++it_){ int c_ = (it_ << 8) + tid;                      \
    __builtin_amdgcn_global_load_lds((const AS1 void*)((src_) + (c_ << 3)),          \
                                     (AS3 void*)((dst_) + (c_ << 3)), 16, 0, 0); } }while(0)

  // ---- cw: full-row coalesced load -> swizzled LDS -> scattered reg read ----
  unsigned cwp[16][2];
  f32x4 am[16];
  {
    char* reg = (char*)smem + (w << 13);       // 8KB per wave
    #pragma unroll
    for (int j = 0; j < 16; ++j){
      f32x4 v = *(const f32x4*)&cw[(qw + j) * 256 + (lane << 2)];  // 1KB burst/instr
      u32x2 d = { pk2(v[0], v[1]), pk2(v[2], v[3]) };
      unsigned off = ((j << 9) + (lane << 3)) ^ ((j & 7) << 4);
      *(u32x2*)(reg + off) = d;
    }
    __syncthreads();
    #pragma unroll
    for (int nt = 0; nt < 16; ++nt){
      unsigned base = ((l15 << 9) + (nt << 5) + (g << 3)) ^ ((l15 & 7) << 4);
      cwp[nt][0] = *(const unsigned*)(reg + base);
      cwp[nt][1] = *(const unsigned*)(reg + base + 4);
      am[nt] = {0.f, 0.f, 0.f, 0.f};
    }
    __syncthreads();
  }

  STG(Kl, Kf + ((size_t)(b * 4) << 14));
  __syncthreads();                       // K(0) staged

  for (int h = 0; h < 4; ++h){
    STG(Vl, Vf + ((size_t)(b * 4 + h) << 14));          // V(h) under QK
    short8 qf0 = *(const short8*)&Qf[(((qblk * 4 + h) * 2 + 0) * 64 + lane) * 8];
    short8 qf1 = *(const short8*)&Qf[(((qblk * 4 + h) * 2 + 1) * 64 + lane) * 8];

    // ---- scores: swapped operands, lane-contiguous ds_read_b128 ----
    f32x4 acc[16];
    #pragma unroll
    for (int nt = 0; nt < 16; ++nt) acc[nt] = {0.f, 0.f, 0.f, 0.f};
    #pragma unroll
    for (int nt = 0; nt < 16; ++nt){
      short8 kf0 = *(const short8*)&Kl[(nt << 10) + (lane << 3)];
      acc[nt] = __builtin_amdgcn_mfma_f32_16x16x32_bf16(kf0, qf0, acc[nt], 0, 0, 0);
      short8 kf1 = *(const short8*)&Kl[(nt << 10) + 512 + (lane << 3)];
      acc[nt] = __builtin_amdgcn_mfma_f32_16x16x32_bf16(kf1, qf1, acc[nt], 0, 0, 0);
    }
    __syncthreads();                     // V(h) ready; all waves done with Kl
    if (h < 3) STG(Kl, Kf + ((size_t)(b * 4 + h + 1) << 14));   // K(h+1) under softmax+PV

    // ---- softmax, fully in-lane (row q = l15; partners at lane^16, lane^32) ----
    float mx = -3.4e38f;
    #pragma unroll
    for (int nt = 0; nt < 16; ++nt){
      float c0 = __uint_as_float(cwp[nt][0] << 16);
      float c1 = __uint_as_float(cwp[nt][0] & 0xffff0000u);
      float c2 = __uint_as_float(cwp[nt][1] << 16);
      float c3 = __uint_as_float(cwp[nt][1] & 0xffff0000u);
      acc[nt][0] = acc[nt][0] * 0.125f + c0;
      acc[nt][1] = acc[nt][1] * 0.125f + c1;
      acc[nt][2] = acc[nt][2] * 0.125f + c2;
      acc[nt][3] = acc[nt][3] * 0.125f + c3;
      mx = fmaxf(mx, fmaxf(fmaxf(acc[nt][0], acc[nt][1]), fmaxf(acc[nt][2], acc[nt][3])));
    }
    mx = fmaxf(mx, __shfl_xor(mx, 16));
    mx = fmaxf(mx, __shfl_xor(mx, 32));
    float sm = 0.f;
    #pragma unroll
    for (int nt = 0; nt < 16; ++nt){
      #pragma unroll
      for (int r = 0; r < 4; ++r){
        float e = __expf(acc[nt][r] - mx);
        acc[nt][r] = e; sm += e;
      }
    }
    sm += __shfl_xor(sm, 16);
    sm += __shfl_xor(sm, 32);
    float inv = 1.f / sm;
    #pragma unroll
    for (int nt = 0; nt < 16; ++nt){
      #pragma unroll
      for (int r = 0; r < 4; ++r){
        float p = acc[nt][r] * inv;
        acc[nt][r] = p;
        am[nt][r] += 0.25f * p;
      }
    }
    // ---- ctx = P @ V : in-lane A packs; lane-contiguous V ds_reads ----
    f32x4 oc[4] = {{0,0,0,0},{0,0,0,0},{0,0,0,0},{0,0,0,0}};
    #pragma unroll
    for (int kk = 0; kk < 8; ++kk){
      union { short8 s; unsigned u[4]; } pa;
      pa.u[0] = pk2(acc[2 * kk][0],     acc[2 * kk][1]);
      pa.u[1] = pk2(acc[2 * kk][2],     acc[2 * kk][3]);
      pa.u[2] = pk2(acc[2 * kk + 1][0], acc[2 * kk + 1][1]);
      pa.u[3] = pk2(acc[2 * kk + 1][2], acc[2 * kk + 1][3]);
      #pragma unroll
      for (int n2 = 0; n2 < 4; ++n2){
        short8 vb = *(const short8*)&Vl[(((kk << 2) + n2) << 9) + (lane << 3)];
        oc[n2] = __builtin_amdgcn_mfma_f32_16x16x32_bf16(pa.s, vb, oc[n2], 0, 0, 0);
      }
    }
    #pragma unroll
    for (int n2 = 0; n2 < 4; ++n2)
      #pragma unroll
      for (int r = 0; r < 4; ++r)
        ctx[(qw + (g << 2) + r) * 256 + (h << 6) + (n2 << 4) + l15] = f2b(oc[n2][r]);

    __syncthreads();                     // K(h+1) ready; all waves done with Vl
  }

  // ---- am: scatter into swizzled LDS, then 1KB-burst coalesced stores ----
  {
    char* reg = (char*)smem + (w << 14);       // 16KB per wave (f32)
    #pragma unroll
    for (int nt = 0; nt < 16; ++nt){
      unsigned off = ((l15 << 10) + (nt << 6) + (g << 4)) ^ ((l15 & 7) << 4);
      *(f32x4*)(reg + off) = am[nt];
    }
    __syncthreads();
    #pragma unroll
    for (int i2 = 0; i2 < 16; ++i2){
      unsigned fb = (tid << 4) + (i2 << 12);   // flat byte 0..65535
      unsigned rowin = (fb >> 10) & 15;
      f32x4 v = *(const f32x4*)((char*)smem + (fb ^ ((rowin & 7) << 4)));
      unsigned row = fb >> 10;                  // 0..63 within block
      *(f32x4*)&am_out[((size_t)b * 4096 + q0 + row) * 256 + ((fb & 1023) >> 2)] = v;
    }
  }
#undef STG
}

extern "C" void kernel_launch(void* const* d_in, const int* in_sizes, int n_in,
                              void* d_out, int out_size, void* d_ws, size_t ws_size,
                              hipStream_t stream)
{
  const float* node_emb = (const float*)d_in[0];
  const float* cluster  = (const float*)d_in[1];
  const float* cw       = (const float*)d_in[2];
  const float* ln_q_g   = (const float*)d_in[3];
  const float* ln_q_b   = (const float*)d_in[4];
  const float* ln_kv_g  = (const float*)d_in[5];
  const float* ln_kv_b  = (const float*)d_in[6];
  const float* ln_o_g   = (const float*)d_in[7];
  const float* ln_o_b   = (const float*)d_in[8];
  const float* W_q  = (const float*)d_in[9];  const float* b_q  = (const float*)d_in[10];
  const float* W_k  = (const float*)d_in[11]; const float* b_k  = (const float*)d_in[12];
  const float* W_v  = (const float*)d_in[13]; const float* b_v  = (const float*)d_in[14];
  const float* W_o  = (const float*)d_in[15]; const float* b_o  = (const float*)d_in[16];
  const float* W_m1 = (const float*)d_in[17]; const float* b_m1 = (const float*)d_in[18];
  const float* W_m2 = (const float*)d_in[19]; const float* b_m2 = (const float*)d_in[20];

  char* ws = (char*)d_ws;
  short* Wbf   = (short*)ws;                                   // 786,432 B (6 x 64K bf16, stage-order)
  short* n1    = (short*)(ws + 786432);                        // 16.78 MB: ctx -> h1
  short* n2    = (short*)(ws + 786432 + 16777216);             // 16.78 MB: Qfrag -> x (bf16)
  short* kfrag = (short*)(ws + 786432 + 2 * 16777216 + 1048576);
  short* vfrag = (short*)(ws + 786432 + 2 * 16777216 + 2 * 1048576);

  float* outF = (float*)d_out;            // first half: final out (written only by M2)
  float* amof = (float*)d_out + 8388608;  // second half: attn_matrix

  hipFuncSetAttribute((const void*)attn_k, hipFuncAttributeMaxDynamicSharedMemorySize, 65536);

  cvt_w<<<1536, 256, 0, stream>>>(W_q, W_k, W_v, W_o, W_m1, W_m2, Wbf);
  // Q projection: fused input-LN, qfrag output -> n2
  gemmW<0,0,0,0,3,1><<<512, 256, 0, stream>>>(nullptr, node_emb, Wbf, b_q,
      nullptr, nullptr, nullptr, n2, ln_q_g, ln_q_b);
  // K / V projections: fused kv-LN from cluster, frag-order outputs
  gemmW<0,0,0,0,1,1><<<32, 256, 0, stream>>>(nullptr, cluster, Wbf + 65536, b_k,
      nullptr, nullptr, nullptr, kfrag, ln_kv_g, ln_kv_b);
  gemmW<0,0,0,0,2,1><<<32, 256, 0, stream>>>(nullptr, cluster, Wbf + 131072, b_v,
      nullptr, nullptr, nullptr, vfrag, ln_kv_g, ln_kv_b);
  // attention (ctx -> n1, attn_matrix -> d_out 2nd half)
  attn_k<<<dim3(64, 8), 256, 65536, stream>>>(n2, kfrag, vfrag, cw, n1, amof);
  // O proj + residual(node_emb f32) -> x as bf16 into n2 (Q dead)
  gemmW<1,0,0,1,0,0><<<512, 256, 0, stream>>>(n1, nullptr, Wbf + 196608, b_o,
      node_emb, nullptr, nullptr, n2, nullptr, nullptr);
  // MLP1 with fused LN(x) prologue + GELU -> n1
  gemmW<0,1,0,1,0,2><<<512, 256, 0, stream>>>(n2, nullptr, Wbf + 262144, b_m1,
      nullptr, nullptr, nullptr, n1, ln_o_g, ln_o_b);
  // MLP2 + residual(x bf16) -> final out f32
  gemmW<2,0,1,0,0,0><<<512, 256, 0, stream>>>(n1, nullptr, Wbf + 327680, b_m2,
      nullptr, n2, outF, nullptr, nullptr, nullptr);
}